// Round 11
// baseline (223.278 us; speedup 1.0000x reference)
//
#include <hip/hip_runtime.h>
#include <math.h>

#define BB 8
#define SS 32
#define HN 64
#define TN 512
#define HID 512

typedef __attribute__((ext_vector_type(8))) short short8;
typedef __attribute__((ext_vector_type(4))) float f32x4;

__device__ __forceinline__ float eluf(float x) { return x > 0.f ? x : (expf(x) - 1.f); }

__device__ __forceinline__ short f2bs(float f) {
    union { float f; unsigned int u; } v; v.f = f;
    unsigned int r = v.u + 0x7fffu + ((v.u >> 16) & 1u);
    return (short)(r >> 16);
}
__device__ __forceinline__ float b2f(short s) {
    union { unsigned int u; float f; } v;
    v.u = ((unsigned int)(unsigned short)s) << 16;
    return v.f;
}

// fp32 -> OCP e4m3fn, RNE, saturating. Subnormals (|x| < 2^-6) via rint(x*512).
__device__ __forceinline__ unsigned char f2f8(float x) {
    union { float f; unsigned u; } v; v.f = x;
    unsigned s = (v.u >> 24) & 0x80;
    unsigned au = v.u & 0x7fffffffu;
    if (au >= 0x43e80000u) return (unsigned char)(s | 0x7e);   // >=464 -> +-448
    if (au < 0x3c800000u) {                                    // |x| < 2^-6
        union { unsigned u; float f; } a; a.u = au;
        int q = (int)rintf(a.f * 512.f);                       // 0..8 (8 -> 2^-6 normal)
        return (unsigned char)(s | (unsigned)q);
    }
    unsigned r = au + 0x7ffffu + ((au >> 20) & 1u);
    unsigned e = (r >> 23) - 120u;
    unsigned m = (r >> 20) & 7u;
    unsigned out = (e << 3) | m;
    if (out > 0x7eu) out = 0x7eu;
    return (unsigned char)(s | out);
}

__device__ __forceinline__ void gld16(const void* g, void* l) {
    __builtin_amdgcn_global_load_lds(
        (const __attribute__((address_space(1))) void*)g,
        (__attribute__((address_space(3))) void*)l, 16, 0, 0);
}

// ---------------------------------------------------------------------------
// 4-wave 128x128 bf16 GEMM core, BK=64 (R7): prep-side GEMMs.
// Ls = 16384 shorts (32KB). OUTB: 0=f32, 1=bf16.
// ---------------------------------------------------------------------------
template <int ACT, int OUTB>
__device__ __forceinline__ void gcore(
    const short* __restrict__ A, const short* __restrict__ B,
    const float* __restrict__ bias, void* __restrict__ Cv,
    int ldc, int K, int m0, int n0, int cm0, short* Ls)
{
    short* Al = Ls;
    short* Bl = Ls + 8192;
    const int tid  = threadIdx.x;
    const int lane = tid & 63;
    const int w    = tid >> 6;
    const int wr   = w >> 1, wc = w & 1;
    const int l16  = lane & 15, quad = lane >> 4;

    const int srow = w * 16 + (lane >> 2);
    const int scol = (lane & 3) * 8;

    f32x4 acc[4][4];
#pragma unroll
    for (int i = 0; i < 4; ++i)
#pragma unroll
        for (int j = 0; j < 4; ++j) { acc[i][j][0]=0.f; acc[i][j][1]=0.f; acc[i][j][2]=0.f; acc[i][j][3]=0.f; }

    short* lA = Al + w * 512;
    short* lB = Bl + w * 512;
    const long rstep = (long)64 * K;

    const short* Ag = A + (long)(m0 + srow) * K + scol;
    const short* Bg = B + (long)(n0 + srow) * K + scol;
    for (int kt = 0; kt < K; kt += 64) {
        __syncthreads();
        gld16(Ag + kt, lA);
        gld16(Ag + kt + rstep, lA + 2048);
        gld16(Ag + kt + 32, lA + 4096);
        gld16(Ag + kt + 32 + rstep, lA + 4096 + 2048);
        gld16(Bg + kt, lB);
        gld16(Bg + kt + rstep, lB + 2048);
        gld16(Bg + kt + 32, lB + 4096);
        gld16(Bg + kt + 32 + rstep, lB + 4096 + 2048);
        __syncthreads();
#pragma unroll
        for (int h = 0; h < 2; ++h) {
            short8 af[4], bf4[4];
#pragma unroll
            for (int mi = 0; mi < 4; ++mi)
                af[mi] = *(const short8*)(Al + h * 4096 + (wr * 64 + mi * 16 + l16) * 32 + quad * 8);
#pragma unroll
            for (int ni = 0; ni < 4; ++ni)
                bf4[ni] = *(const short8*)(Bl + h * 4096 + (wc * 64 + ni * 16 + l16) * 32 + quad * 8);
#pragma unroll
            for (int mi = 0; mi < 4; ++mi)
#pragma unroll
                for (int ni = 0; ni < 4; ++ni)
                    acc[mi][ni] = __builtin_amdgcn_mfma_f32_16x16x32_bf16(af[mi], bf4[ni], acc[mi][ni], 0, 0, 0);
        }
    }

    __syncthreads();

    float bv[4];
#pragma unroll
    for (int ni = 0; ni < 4; ++ni)
        bv[ni] = bias ? bias[n0 + wc * 64 + ni * 16 + l16] : 0.f;

    if (OUTB == 1) {
        short* eb = Ls + w * 1152;
        const int er = lane >> 2;
        const int ec = (lane & 3) * 16;
#pragma unroll
        for (int mi = 0; mi < 4; ++mi) {
#pragma unroll
            for (int ni = 0; ni < 4; ++ni)
#pragma unroll
                for (int r = 0; r < 4; ++r) {
                    float x = acc[mi][ni][r] + bv[ni];
                    if (ACT == 1) x = eluf(x);
                    eb[(quad * 4 + r) * 72 + ni * 16 + l16] = f2bs(x);
                }
            __builtin_amdgcn_sched_barrier(0);
            short8 v0 = *(const short8*)&eb[er * 72 + ec];
            short8 v1 = *(const short8*)&eb[er * 72 + ec + 8];
            long cb = (long)(cm0 + wr * 64 + mi * 16 + er) * ldc + n0 + wc * 64 + ec;
            *(short8*)((short*)Cv + cb)     = v0;
            *(short8*)((short*)Cv + cb + 8) = v1;
            __builtin_amdgcn_sched_barrier(0);
        }
    } else {
#pragma unroll
        for (int mi = 0; mi < 4; ++mi)
#pragma unroll
            for (int ni = 0; ni < 4; ++ni) {
                int gc = n0 + wc * 64 + ni * 16 + l16;
#pragma unroll
                for (int r = 0; r < 4; ++r) {
                    float x = acc[mi][ni][r] + bv[ni];
                    if (ACT == 1) x = eluf(x);
                    ((float*)Cv)[(long)(cm0 + wr * 64 + mi * 16 + quad * 4 + r) * ldc + gc] = x;
                }
            }
    }
}

// ---------------------------------------------------------------------------
// gh core: bf16 BK=128 dual GEMM (P@tkWT + tq@Wtout2), tanh, fp8 OUT.
// Ls = 32768 shorts (64KB).
// ---------------------------------------------------------------------------
__device__ __forceinline__ void gcore_gh(
    const short* __restrict__ A, const short* __restrict__ B,
    const short* __restrict__ A2, const short* __restrict__ B2,
    unsigned char* __restrict__ C8,
    int m0, int n0, int cm0, short* Ls)
{
    short* Al = Ls;
    short* Bl = Ls + 16384;
    const int tid  = threadIdx.x;
    const int lane = tid & 63;
    const int w    = tid >> 6;
    const int wr   = w >> 1, wc = w & 1;
    const int l16  = lane & 15, quad = lane >> 4;

    const int srow = w * 16 + (lane >> 2);
    const int scol = (lane & 3) * 8;

    f32x4 acc[4][4];
#pragma unroll
    for (int i = 0; i < 4; ++i)
#pragma unroll
        for (int j = 0; j < 4; ++j) { acc[i][j][0]=0.f; acc[i][j][1]=0.f; acc[i][j][2]=0.f; acc[i][j][3]=0.f; }

    short* lA = Al + w * 512;
    short* lB = Bl + w * 512;
    const long rstep = (long)64 * 512;

    for (int rep = 0; rep <= 1; ++rep) {
        const short* Ag = (rep ? A2 : A) + (long)(m0 + srow) * 512 + scol;
        const short* Bg = (rep ? B2 : B) + (long)(n0 + srow) * 512 + scol;
        for (int kt = 0; kt < 512; kt += 128) {
            __syncthreads();
#pragma unroll
            for (int h = 0; h < 4; ++h) {
                gld16(Ag + kt + h * 32,         lA + h * 4096);
                gld16(Ag + kt + h * 32 + rstep, lA + h * 4096 + 2048);
                gld16(Bg + kt + h * 32,         lB + h * 4096);
                gld16(Bg + kt + h * 32 + rstep, lB + h * 4096 + 2048);
            }
            __syncthreads();
#pragma unroll
            for (int h = 0; h < 4; ++h) {
                short8 af[4], bf4[4];
#pragma unroll
                for (int mi = 0; mi < 4; ++mi)
                    af[mi] = *(const short8*)(Al + h * 4096 + (wr * 64 + mi * 16 + l16) * 32 + quad * 8);
#pragma unroll
                for (int ni = 0; ni < 4; ++ni)
                    bf4[ni] = *(const short8*)(Bl + h * 4096 + (wc * 64 + ni * 16 + l16) * 32 + quad * 8);
#pragma unroll
                for (int mi = 0; mi < 4; ++mi)
#pragma unroll
                    for (int ni = 0; ni < 4; ++ni)
                        acc[mi][ni] = __builtin_amdgcn_mfma_f32_16x16x32_bf16(af[mi], bf4[ni], acc[mi][ni], 0, 0, 0);
            }
        }
    }

    __syncthreads();

    // tanh -> fp8, LDS-vectorized 16B stores
    unsigned char* eb = (unsigned char*)Ls + w * 1280;   // 16 rows x 80B stride
    const int er = lane >> 2;
    const int ec = (lane & 3) * 16;
#pragma unroll
    for (int mi = 0; mi < 4; ++mi) {
#pragma unroll
        for (int ni = 0; ni < 4; ++ni)
#pragma unroll
            for (int r = 0; r < 4; ++r)
                eb[(quad * 4 + r) * 80 + ni * 16 + l16] = f2f8(tanhf(acc[mi][ni][r]));
        __builtin_amdgcn_sched_barrier(0);
        int4 v = *(const int4*)(eb + er * 80 + ec);
        *(int4*)(C8 + (long)(cm0 + wr * 64 + mi * 16 + er) * 512 + n0 + wc * 64 + ec) = v;
        __builtin_amdgcn_sched_barrier(0);
    }
}

// ---------------------------------------------------------------------------
// fp8 GEMM core, 128x128 tile, BK=256 (8 chunks x [128 rows][32 B]).
// 2 barrier drains per K=512. Ls = 65536 bytes. OUTB: 1=bf16 C, 2=hs-mode.
// ---------------------------------------------------------------------------
template <int OUTB>
__device__ __forceinline__ void gcoreF(
    const unsigned char* __restrict__ A, const unsigned char* __restrict__ B,
    const float* __restrict__ bias, void* __restrict__ Cv,
    int ldc, int m0, int n0, int cm0, unsigned char* Ls,
    const float* __restrict__ hq, float* __restrict__ hsp)
{
    unsigned char* Al = Ls;
    unsigned char* Bl = Ls + 32768;
    const int tid  = threadIdx.x;
    const int lane = tid & 63;
    const int w    = tid >> 6;
    const int wr   = w >> 1, wc = w & 1;
    const int l16  = lane & 15, quad = lane >> 4;

    const int srow = w * 32 + (lane >> 1);    // 128 rows across 4 waves
    const int scol = (lane & 1) * 16;         // byte offset in 32B row

    f32x4 acc[4][4];
#pragma unroll
    for (int i = 0; i < 4; ++i)
#pragma unroll
        for (int j = 0; j < 4; ++j) { acc[i][j][0]=0.f; acc[i][j][1]=0.f; acc[i][j][2]=0.f; acc[i][j][3]=0.f; }

    const unsigned char* Ag = A + (long)(m0 + srow) * 512 + scol;
    const unsigned char* Bg = B + (long)(n0 + srow) * 512 + scol;
    unsigned char* lA = Al + w * 1024;
    unsigned char* lB = Bl + w * 1024;

    for (int kt = 0; kt < 512; kt += 256) {
        __syncthreads();
#pragma unroll
        for (int h = 0; h < 8; ++h) {
            gld16(Ag + kt + h * 32, lA + h * 4096);
            gld16(Bg + kt + h * 32, lB + h * 4096);
        }
        __syncthreads();
#pragma unroll
        for (int h = 0; h < 8; ++h) {
            long af[4], bf4[4];
#pragma unroll
            for (int mi = 0; mi < 4; ++mi)
                af[mi] = *(const long*)(Al + h * 4096 + (wr * 64 + mi * 16 + l16) * 32 + quad * 8);
#pragma unroll
            for (int ni = 0; ni < 4; ++ni)
                bf4[ni] = *(const long*)(Bl + h * 4096 + (wc * 64 + ni * 16 + l16) * 32 + quad * 8);
#pragma unroll
            for (int mi = 0; mi < 4; ++mi)
#pragma unroll
                for (int ni = 0; ni < 4; ++ni)
                    acc[mi][ni] = __builtin_amdgcn_mfma_f32_16x16x32_fp8_fp8(af[mi], bf4[ni], acc[mi][ni], 0, 0, 0);
        }
    }

    __syncthreads();

    float bv[4];
#pragma unroll
    for (int ni = 0; ni < 4; ++ni)
        bv[ni] = bias ? bias[n0 + wc * 64 + ni * 16 + l16] : 0.f;

    if (OUTB == 1) {
        short* eb = (short*)Ls + w * 1152;
        const int er = lane >> 2;
        const int ec = (lane & 3) * 16;
#pragma unroll
        for (int mi = 0; mi < 4; ++mi) {
#pragma unroll
            for (int ni = 0; ni < 4; ++ni)
#pragma unroll
                for (int r = 0; r < 4; ++r)
                    eb[(quad * 4 + r) * 72 + ni * 16 + l16] = f2bs(acc[mi][ni][r] + bv[ni]);
            __builtin_amdgcn_sched_barrier(0);
            short8 v0 = *(const short8*)&eb[er * 72 + ec];
            short8 v1 = *(const short8*)&eb[er * 72 + ec + 8];
            long cb = (long)(cm0 + wr * 64 + mi * 16 + er) * ldc + n0 + wc * 64 + ec;
            *(short8*)((short*)Cv + cb)     = v0;
            *(short8*)((short*)Cv + cb + 8) = v1;
            __builtin_amdgcn_sched_barrier(0);
        }
    } else {
        // hs-mode: hs[row] = sum_col elu(acc + b) * hq[n][col]; wave-row = one n
        const int n_w = (cm0 + wr * 64) >> 6;
        float hqv[4];
#pragma unroll
        for (int ni = 0; ni < 4; ++ni)
            hqv[ni] = hq[(long)n_w * 512 + n0 + wc * 64 + ni * 16 + l16];
        float* red = (float*)Ls;                   // [4 waves][64 rows]
#pragma unroll
        for (int mi = 0; mi < 4; ++mi)
#pragma unroll
            for (int r = 0; r < 4; ++r) {
                float p = 0.f;
#pragma unroll
                for (int ni = 0; ni < 4; ++ni)
                    p += eluf(acc[mi][ni][r] + bv[ni]) * hqv[ni];
                p += __shfl_xor(p, 1);
                p += __shfl_xor(p, 2);
                p += __shfl_xor(p, 4);
                p += __shfl_xor(p, 8);
                if (l16 == 0) red[w * 64 + mi * 16 + quad * 4 + r] = p;
            }
        __syncthreads();
        if (tid < 128) {
            int wr2 = tid >> 6, rw = tid & 63;
            float v = red[(wr2 * 2 + 0) * 64 + rw] + red[(wr2 * 2 + 1) * 64 + rw];
            hsp[(long)(n0 >> 7) * 16384 + cm0 + tid] = v;
        }
    }
}

// scores: fp8 tq8 @ tk8^T -> bf16 scb. XCD-swizzled (y16 x z8).
__global__ __launch_bounds__(256) void mgemm_f8(
    const unsigned char* __restrict__ A, const unsigned char* __restrict__ B,
    short* __restrict__ Cb)
{
    __shared__ unsigned char Ls[65536];
    const int bid = blockIdx.x;
    const int g = (bid & 7) + 8 * (bid >> 5);
    const int x = (bid >> 3) & 3;
    const int y = g & 15;
    const int z = g >> 4;
    gcoreF<1>(A + (long)z * 2048 * 512, B + (long)z * 262144, nullptr,
              Cb + (long)z * 2048 * 512, 512, y * 128, x * 128, y * 128, Ls,
              nullptr, nullptr);
}

// hs: fp8 gh8 @ Whk8^T, epilogue dots with hq -> hsp. Swizzled, y in [0,128).
__global__ __launch_bounds__(256) void mgemm_hs8(
    const unsigned char* __restrict__ A, const unsigned char* __restrict__ B,
    const float* __restrict__ bias, const float* __restrict__ hq, float* __restrict__ hsp)
{
    __shared__ unsigned char Ls[65536];
    const int bid = blockIdx.x;
    const int y = (bid & 7) + 8 * (bid >> 5);
    const int x = (bid >> 3) & 3;
    gcoreF<2>(A, B, bias, nullptr, 512, y * 128, x * 128, y * 128, Ls, hq, hsp);
}

// gh: bf16 dual GEMM -> tanh -> fp8 gh8. Swizzled (y16 x z8).
__global__ __launch_bounds__(256) void mgemm_gh(
    const short* __restrict__ Pb, const short* __restrict__ tkWTb,
    const short* __restrict__ tqb, const short* __restrict__ WTo2,
    unsigned char* __restrict__ gh8)
{
    __shared__ short Ls[32768];
    const int bid = blockIdx.x;
    const int g = (bid & 7) + 8 * (bid >> 5);
    const int x = (bid >> 3) & 3;
    const int y = g & 15;
    const int z = g >> 4;
    gcore_gh(Pb + (long)z * 2048 * 512, tkWTb + (long)z * 262144,
             tqb + (long)z * 2048 * 512, WTo2,
             gh8 + (long)z * 2048 * 512, y * 128, x * 128, y * 128, Ls);
}

// qall (48) | qe (16) | tk (128) in one launch (BK=64 bf16 core)
__global__ __launch_bounds__(256) void mgemm_multi(
    const short* __restrict__ decb, const short* __restrict__ WTall, float* __restrict__ qall,
    const short* __restrict__ embAll, const short* __restrict__ WTe, float* __restrict__ qe,
    const short* __restrict__ WTk, const float* __restrict__ b_tk, short* __restrict__ tkb)
{
    __shared__ short Ls[16384];
    int id = blockIdx.x;
    if (id < 48) {
        int y = id >> 4, x = id & 15;
        gcore<0, 0>(decb, WTall, nullptr, qall, 2048, 512, y * 128, x * 128, y * 128, Ls);
    } else if (id < 64) {
        int id2 = id - 48, y = id2 >> 2, x = id2 & 3;
        gcore<0, 0>(embAll, WTe, nullptr, qe, 512, 512, y * 128, x * 128, y * 128, Ls);
    } else {
        int id3 = id - 64, y = id3 >> 2, x = id3 & 3;
        gcore<1, 1>(embAll, WTk, b_tk, tkb, 512, 512, 512 + y * 128, x * 128, y * 128, Ls);
    }
}

// ---------------------------------------------------------------------------
// prep: float4 casts | gathers | transpose-cast 9 weights (slab 8 -> fp8)
// ---------------------------------------------------------------------------
struct WTDesc { const float* src[9]; short* dst[9]; };

__global__ __launch_bounds__(256) void prep(
    const float* __restrict__ dec_out, const float* __restrict__ history,
    short* __restrict__ decb,
    const float* __restrict__ emb, const int* __restrict__ head, const int* __restrict__ tail,
    short* __restrict__ embAll, WTDesc wd)
{
    __shared__ float t[32][33];
    const int id = blockIdx.x, tid = threadIdx.x;
    if (id < 132) {
        int i = (id * 256 + tid) * 4;
        float4 v = (i < 131072) ? *(const float4*)(dec_out + i)
                                : *(const float4*)(history + (i - 131072));
        short4 o;
        o.x = f2bs(v.x); o.y = f2bs(v.y); o.z = f2bs(v.z); o.w = f2bs(v.w);
        *(short4*)(decb + i) = o;
    } else if (id < 132 + 2304) {
        int r = (id - 132) * 2 + (tid >> 7);
        int c4 = (tid & 127) * 4;
        int idx = (r < 512) ? head[r] : tail[r - 512];
        float4 v = *(const float4*)(emb + (long)idx * 512 + c4);
        short4 o;
        o.x = f2bs(v.x); o.y = f2bs(v.y); o.z = f2bs(v.z); o.w = f2bs(v.w);
        *(short4*)(embAll + (long)r * 512 + c4) = o;
    } else {
        int q = id - 2436;
        int z = q >> 8, xy = q & 255;
        int x = xy & 15, y = xy >> 4;
        const float* src = wd.src[z];
        int k0 = y * 32, n0 = x * 32;
        int tx = tid & 31, ty = tid >> 5;
#pragma unroll
        for (int i = 0; i < 32; i += 8)
            t[ty + i][tx] = src[(long)(k0 + ty + i) * 512 + n0 + tx];
        __syncthreads();
        if (z == 8) {   // Whk^T -> fp8 (consumer: hs fp8 GEMM)
            unsigned char* d8 = (unsigned char*)wd.dst[z];
#pragma unroll
            for (int i = 0; i < 32; i += 8)
                d8[(long)(n0 + ty + i) * 512 + k0 + tx] = f2f8(t[tx][ty + i]);
        } else {
            short* dst = wd.dst[z];
#pragma unroll
            for (int i = 0; i < 32; i += 8)
                dst[(long)(n0 + ty + i) * 512 + k0 + tx] = f2bs(t[tx][ty + i]);
        }
    }
}

// ---------------------------------------------------------------------------
// L3: build_tq (8192, dual bf16+fp8) | tkWT GEMM (128) | hq (128) | tk->fp8 (512)
// ---------------------------------------------------------------------------
__global__ __launch_bounds__(256) void l3_kernel(
    const float* __restrict__ qall, const float* __restrict__ qe,
    const float* __restrict__ b_tq, short* __restrict__ tqb, unsigned char* __restrict__ tq8,
    const short* __restrict__ WTo1, const short* __restrict__ tkb, short* __restrict__ tkWTb,
    const float* __restrict__ b_hq, float* __restrict__ hqf, unsigned char* __restrict__ tk8)
{
    __shared__ short Ls[16384];
    if (blockIdx.x < 8192) {
        long gid = (long)blockIdx.x * 256 + threadIdx.x;
        int r = (int)(gid >> 7), j0 = ((int)gid & 127) * 4;
        int b = r >> 11, rem = r & 2047, s = rem >> 6, h = rem & 63;
        float4 d = *(const float4*)(qall + (long)(b * 32 + s) * 2048 + j0);
        float4 q = *(const float4*)(qall + (long)(256 + b) * 2048 + 1024 + j0);
        float4 e = *(const float4*)(qe + (long)(b * 64 + h) * 512 + j0);
        float4 bb = *(const float4*)(b_tq + j0);
        float f0 = eluf(d.x + q.x + e.x + bb.x);
        float f1 = eluf(d.y + q.y + e.y + bb.y);
        float f2 = eluf(d.z + q.z + e.z + bb.z);
        float f3 = eluf(d.w + q.w + e.w + bb.w);
        short4 o;
        o.x = f2bs(f0); o.y = f2bs(f1); o.z = f2bs(f2); o.w = f2bs(f3);
        *(short4*)(tqb + (long)r * 512 + j0) = o;
        uchar4 o8;
        o8.x = f2f8(f0); o8.y = f2f8(f1); o8.z = f2f8(f2); o8.w = f2f8(f3);
        *(uchar4*)(tq8 + (long)r * 512 + j0) = o8;
    } else if (blockIdx.x < 8320) {
        int id2 = blockIdx.x - 8192;
        int z = id2 >> 4, r = id2 & 15;
        int x = r & 3, y = r >> 2;
        gcore<0, 1>(WTo1, tkb + (long)z * 262144, nullptr,
                    tkWTb + (long)z * 262144, 512, 512, y * 128, x * 128, y * 128, Ls);
    } else if (blockIdx.x < 8448) {
        long gid = (long)(blockIdx.x - 8320) * 256 + threadIdx.x;
        int n = (int)(gid >> 7), j0 = ((int)gid & 127) * 4;
        int b = n >> 5;
        float4 d = *(const float4*)(qall + (long)n * 2048 + 512 + j0);
        float4 h2 = *(const float4*)(qall + (long)(256 + b) * 2048 + 1536 + j0);
        float4 bb = *(const float4*)(b_hq + j0);
        float4 o;
        o.x = eluf(d.x + h2.x + bb.x);
        o.y = eluf(d.y + h2.y + bb.y);
        o.z = eluf(d.z + h2.z + bb.z);
        o.w = eluf(d.w + h2.w + bb.w);
        *(float4*)(hqf + (long)n * 512 + j0) = o;
    } else {
        // tk bf16 -> fp8 (2,097,152 elems, 16/thread, 512 blocks)
        long base = ((long)(blockIdx.x - 8448) * 256 + threadIdx.x) * 16;
        short8 a0 = *(const short8*)(tkb + base);
        short8 a1 = *(const short8*)(tkb + base + 8);
        unsigned int p[4];
#pragma unroll
        for (int j = 0; j < 2; ++j) {
            p[j] = (unsigned)f2f8(b2f(a0[j*4+0])) | ((unsigned)f2f8(b2f(a0[j*4+1])) << 8)
                 | ((unsigned)f2f8(b2f(a0[j*4+2])) << 16) | ((unsigned)f2f8(b2f(a0[j*4+3])) << 24);
            p[2+j] = (unsigned)f2f8(b2f(a1[j*4+0])) | ((unsigned)f2f8(b2f(a1[j*4+1])) << 8)
                 | ((unsigned)f2f8(b2f(a1[j*4+2])) << 16) | ((unsigned)f2f8(b2f(a1[j*4+3])) << 24);
        }
        *(uint4*)(tk8 + base) = make_uint4(p[0], p[1], p[2], p[3]);
    }
}

// mask + row softmax over 512: bf16 scores -> bf16 P. 4 rows/block.
__global__ __launch_bounds__(256) void sm_kernel(
    const short* __restrict__ sc, const int* __restrict__ adj, const int* __restrict__ dup,
    short* __restrict__ Pb)
{
    int w = threadIdx.x >> 6, lane = threadIdx.x & 63;
    long r = (long)blockIdx.x * 4 + w;
    int b = (int)(r >> 11), rem = (int)(r & 2047), s = rem >> 6, h = rem & 63;
    const short* row = sc + r * 512 + lane * 8;
    const int* adjr = adj + ((long)(b * 64 + h)) * 512 + lane * 8;
    const int* dupr = dup + ((long)(b * 32 + s)) * 512 + lane * 8;
    short8 v8 = *(const short8*)row;
    int4 a0 = *(const int4*)adjr, a1 = *(const int4*)(adjr + 4);
    int4 d0 = *(const int4*)dupr, d1 = *(const int4*)(dupr + 4);
    int am[8] = {a0.x, a0.y, a0.z, a0.w, a1.x, a1.y, a1.z, a1.w};
    int dm[8] = {d0.x, d0.y, d0.z, d0.w, d1.x, d1.y, d1.z, d1.w};
    float v[8];
    float m = -INFINITY;
#pragma unroll
    for (int i = 0; i < 8; ++i) {
        v[i] = (am[i] && !dm[i]) ? b2f(v8[i]) : -INFINITY;
        m = fmaxf(m, v[i]);
    }
#pragma unroll
    for (int d = 32; d >= 1; d >>= 1) m = fmaxf(m, __shfl_xor(m, d));
    float sum = 0.f;
#pragma unroll
    for (int i = 0; i < 8; ++i) {
        float e = (m == -INFINITY) ? 0.f : expf(v[i] - m);
        v[i] = e; sum += e;
    }
#pragma unroll
    for (int d = 32; d >= 1; d >>= 1) sum += __shfl_xor(sum, d);
    float inv = sum > 0.f ? 1.f / sum : 0.f;
    short8 o;
#pragma unroll
    for (int i = 0; i < 8; ++i) o[i] = f2bs(v[i] * inv);
    *(short8*)(Pb + r * 512 + lane * 8) = o;
}

// head softmax (from hsp partials) + prob + log; one block per n
__global__ __launch_bounds__(256) void fused_head(
    const float* __restrict__ hsp, const int* __restrict__ head,
    const short* __restrict__ ta, float* __restrict__ out)
{
    int n = blockIdx.x, b = n >> 5;
    int tid = threadIdx.x;
    __shared__ float hal[64];
    __shared__ float part[4][512];

    if (tid < 64) {
        float sv_raw = hsp[n * 64 + tid] + hsp[16384 + n * 64 + tid]
                     + hsp[2 * 16384 + n * 64 + tid] + hsp[3 * 16384 + n * 64 + tid];
        int hv = head[b * 64 + tid];
        unsigned long long ball = __ballot(hv != 0);
        int len = __popcll(ball);
        float sv = (tid < len) ? sv_raw : -INFINITY;
        float m = sv;
#pragma unroll
        for (int d = 32; d >= 1; d >>= 1) m = fmaxf(m, __shfl_xor(m, d));
        float e = expf(sv - m);
        float sum = e;
#pragma unroll
        for (int d = 32; d >= 1; d >>= 1) sum += __shfl_xor(sum, d);
        hal[tid] = e / sum;
    }
    __syncthreads();

    {
        int w = tid >> 6, lane = tid & 63;
        const short* tab = ta + (long)n * 64 * 512 + (long)(w * 16) * 512 + lane * 8;
        float acc[8] = {};
#pragma unroll
        for (int k = 0; k < 16; ++k) {
            float a = hal[w * 16 + k];
            short8 tv = *(const short8*)(tab + (long)k * 512);
#pragma unroll
            for (int u = 0; u < 8; ++u) acc[u] += a * b2f(tv[u]);
        }
        float4* pp = (float4*)&part[w][lane * 8];
        pp[0] = make_float4(acc[0], acc[1], acc[2], acc[3]);
        pp[1] = make_float4(acc[4], acc[5], acc[6], acc[7]);
    }
    __syncthreads();

    for (int t = tid; t < 512; t += 256) {
        float a = part[0][t] + part[1][t] + part[2][t] + part[3][t];
        out[(long)n * 512 + t] = logf(a + 1e-20f);
    }
}

extern "C" void kernel_launch(void* const* d_in, const int* in_sizes, int n_in,
                              void* d_out, int out_size, void* d_ws, size_t ws_size,
                              hipStream_t stream)
{
    const float* dec_out = (const float*)d_in[0];
    const float* history = (const float*)d_in[1];
    const int*   head    = (const int*)d_in[2];
    const int*   tail    = (const int*)d_in[3];
    const int*   adj     = (const int*)d_in[4];
    const int*   dup     = (const int*)d_in[5];
    const float* emb     = (const float*)d_in[6];
    const float* W_tq    = (const float*)d_in[7];
    const float* b_tq    = (const float*)d_in[8];
    const float* W_tk    = (const float*)d_in[9];
    const float* b_tk    = (const float*)d_in[10];
    const float* W_tout  = (const float*)d_in[11];
    const float* W_hq    = (const float*)d_in[12];
    const float* b_hq    = (const float*)d_in[13];
    const float* W_hk    = (const float*)d_in[14];
    const float* b_hk    = (const float*)d_in[15];
    float* out = (float*)d_out;

    char* ws = (char*)d_ws;
    auto alloc = [&](size_t bytes) -> void* {
        char* p = ws;
        ws += (bytes + 255) & ~(size_t)255;
        return (void*)p;
    };
    short* decb   = (short*)alloc((size_t)384 * 512 * 2);    // dec 0..255, hist 256..263
    short* embAll = (short*)alloc((size_t)4608 * 512 * 2);   // head 0..511, tail 512..4607
    short* WT     = (short*)alloc((size_t)9 * 512 * 512 * 2);
    float* qall   = (float*)alloc((size_t)384 * 2048 * 4);   // [qd|hqp|qh'|hq2']
    float* qe     = (float*)alloc((size_t)512 * 512 * 4);
    float* hqf    = (float*)alloc((size_t)256 * 512 * 4);
    float* hsp    = (float*)alloc((size_t)4 * 16384 * 4);    // hscores col-block partials
    short* tkb    = (short*)alloc((size_t)4096 * 512 * 2);
    short* tkWTb  = (short*)alloc((size_t)4096 * 512 * 2);
    short* tqb    = (short*)alloc((size_t)16384 * 512 * 2);
    short* scb    = (short*)alloc((size_t)16384 * 512 * 2);  // scores bf16, reused as gh8
    short* Pb     = (short*)alloc((size_t)16384 * 512 * 2);  // tail_attn bf16 (to the end)
    unsigned char* tq8 = (unsigned char*)alloc((size_t)16384 * 512);
    unsigned char* tk8 = (unsigned char*)alloc((size_t)4096 * 512);
    unsigned char* gh8 = (unsigned char*)scb;   // scores dead after sm

    // WT slab: 0 Wd^T | 1 Whq1^T | 2 Wtq2^T | 3 Whq2^T | 4 We^T | 5 Wtk^T
    //          6 Wtout1^T | 7 Wtout2^T (bf16) | 8 Whk^T (fp8!)
    WTDesc wd;
    wd.src[0] = W_tq;               wd.dst[0] = WT;
    wd.src[1] = W_hq;               wd.dst[1] = WT + (size_t)1 * 262144;
    wd.src[2] = W_tq + 512 * 512;   wd.dst[2] = WT + (size_t)2 * 262144;
    wd.src[3] = W_hq + 512 * 512;   wd.dst[3] = WT + (size_t)3 * 262144;
    wd.src[4] = W_tq + 1024 * 512;  wd.dst[4] = WT + (size_t)4 * 262144;
    wd.src[5] = W_tk;               wd.dst[5] = WT + (size_t)5 * 262144;
    wd.src[6] = W_tout;             wd.dst[6] = WT + (size_t)6 * 262144;
    wd.src[7] = W_tout + 512 * 512; wd.dst[7] = WT + (size_t)7 * 262144;
    wd.src[8] = W_hk;               wd.dst[8] = WT + (size_t)8 * 262144;

    // 1: casts / gathers / weight transposes
    prep<<<4740, 256, 0, stream>>>(dec_out, history, decb, emb, head, tail, embAll, wd);
    // 2: qall | qe | tk (bf16)
    mgemm_multi<<<192, 256, 0, stream>>>(decb, WT, qall, embAll, WT + (size_t)4 * 262144, qe,
                                         WT + (size_t)5 * 262144, b_tk, tkb);
    // 3: tq (bf16+fp8) | tkWT | hq | tk->fp8
    l3_kernel<<<8960, 256, 0, stream>>>(qall, qe, b_tq, tqb, tq8, WT + (size_t)6 * 262144,
                                        tkb, tkWTb, b_hq, hqf, tk8);
    // 4: scores = tq8 @ tk8^T (fp8, BK=256, 2 drains), bf16 out, swizzled
    mgemm_f8<<<512, 256, 0, stream>>>(tq8, tk8, scb);
    // 5: mask + softmax -> P (bf16 — fp8 would flush small attn weights and
    //    wreck log(prob) for low-prob outputs)
    sm_kernel<<<4096, 256, 0, stream>>>(scb, adj, dup, Pb);
    // 6: gh = tanh(P @ tkWT^T + tq @ Wtout2^T) bf16 dual, fp8 out (over scb)
    mgemm_gh<<<512, 256, 0, stream>>>(Pb, tkWTb, tqb, WT + (size_t)7 * 262144, gh8);
    // 7: hs partials = elu(gh8 @ Whk8^T + b_hk) . hq (fp8, BK=256), swizzled
    mgemm_hs8<<<512, 256, 0, stream>>>(gh8, (const unsigned char*)(WT + (size_t)8 * 262144),
                                       b_hk, hqf, hsp);
    // 8: head softmax + prob + log
    fused_head<<<256, 256, 0, stream>>>(hsp, head, Pb, out);
}

// Round 12
// 211.128 us; speedup vs baseline: 1.0575x; 1.0575x over previous
//
#include <hip/hip_runtime.h>
#include <math.h>

#define BB 8
#define SS 32
#define HN 64
#define TN 512
#define HID 512

typedef __attribute__((ext_vector_type(8))) short short8;
typedef __attribute__((ext_vector_type(4))) float f32x4;

__device__ __forceinline__ float eluf(float x) { return x > 0.f ? x : (expf(x) - 1.f); }

__device__ __forceinline__ short f2bs(float f) {
    union { float f; unsigned int u; } v; v.f = f;
    unsigned int r = v.u + 0x7fffu + ((v.u >> 16) & 1u);
    return (short)(r >> 16);
}
__device__ __forceinline__ float b2f(short s) {
    union { unsigned int u; float f; } v;
    v.u = ((unsigned int)(unsigned short)s) << 16;
    return v.f;
}

__device__ __forceinline__ void gld16(const void* g, void* l) {
    __builtin_amdgcn_global_load_lds(
        (const __attribute__((address_space(1))) void*)g,
        (__attribute__((address_space(3))) void*)l, 16, 0, 0);
}

// ---------------------------------------------------------------------------
// 4-wave 128x128 GEMM core, BK=64 (R7): prep-side GEMMs (qall/qe/tk/tkWT).
// Ls = 16384 shorts (32KB). OUTB: 0=f32, 1=bf16.
// ---------------------------------------------------------------------------
template <int ACT, int OUTB>
__device__ __forceinline__ void gcore(
    const short* __restrict__ A, const short* __restrict__ B,
    const float* __restrict__ bias, void* __restrict__ Cv,
    int ldc, int K, int m0, int n0, int cm0, short* Ls)
{
    short* Al = Ls;
    short* Bl = Ls + 8192;
    const int tid  = threadIdx.x;
    const int lane = tid & 63;
    const int w    = tid >> 6;
    const int wr   = w >> 1, wc = w & 1;
    const int l16  = lane & 15, quad = lane >> 4;

    const int srow = w * 16 + (lane >> 2);
    const int scol = (lane & 3) * 8;

    f32x4 acc[4][4];
#pragma unroll
    for (int i = 0; i < 4; ++i)
#pragma unroll
        for (int j = 0; j < 4; ++j) { acc[i][j][0]=0.f; acc[i][j][1]=0.f; acc[i][j][2]=0.f; acc[i][j][3]=0.f; }

    short* lA = Al + w * 512;
    short* lB = Bl + w * 512;
    const long rstep = (long)64 * K;

    const short* Ag = A + (long)(m0 + srow) * K + scol;
    const short* Bg = B + (long)(n0 + srow) * K + scol;
    for (int kt = 0; kt < K; kt += 64) {
        __syncthreads();
        gld16(Ag + kt, lA);
        gld16(Ag + kt + rstep, lA + 2048);
        gld16(Ag + kt + 32, lA + 4096);
        gld16(Ag + kt + 32 + rstep, lA + 4096 + 2048);
        gld16(Bg + kt, lB);
        gld16(Bg + kt + rstep, lB + 2048);
        gld16(Bg + kt + 32, lB + 4096);
        gld16(Bg + kt + 32 + rstep, lB + 4096 + 2048);
        __syncthreads();
#pragma unroll
        for (int h = 0; h < 2; ++h) {
            short8 af[4], bf4[4];
#pragma unroll
            for (int mi = 0; mi < 4; ++mi)
                af[mi] = *(const short8*)(Al + h * 4096 + (wr * 64 + mi * 16 + l16) * 32 + quad * 8);
#pragma unroll
            for (int ni = 0; ni < 4; ++ni)
                bf4[ni] = *(const short8*)(Bl + h * 4096 + (wc * 64 + ni * 16 + l16) * 32 + quad * 8);
#pragma unroll
            for (int mi = 0; mi < 4; ++mi)
#pragma unroll
                for (int ni = 0; ni < 4; ++ni)
                    acc[mi][ni] = __builtin_amdgcn_mfma_f32_16x16x32_bf16(af[mi], bf4[ni], acc[mi][ni], 0, 0, 0);
        }
    }

    __syncthreads();

    float bv[4];
#pragma unroll
    for (int ni = 0; ni < 4; ++ni)
        bv[ni] = bias ? bias[n0 + wc * 64 + ni * 16 + l16] : 0.f;

    if (OUTB == 1) {
        short* eb = Ls + w * 1152;
        const int er = lane >> 2;
        const int ec = (lane & 3) * 16;
#pragma unroll
        for (int mi = 0; mi < 4; ++mi) {
#pragma unroll
            for (int ni = 0; ni < 4; ++ni)
#pragma unroll
                for (int r = 0; r < 4; ++r) {
                    float x = acc[mi][ni][r] + bv[ni];
                    if (ACT == 1) x = eluf(x);
                    eb[(quad * 4 + r) * 72 + ni * 16 + l16] = f2bs(x);
                }
            __builtin_amdgcn_sched_barrier(0);
            short8 v0 = *(const short8*)&eb[er * 72 + ec];
            short8 v1 = *(const short8*)&eb[er * 72 + ec + 8];
            long cb = (long)(cm0 + wr * 64 + mi * 16 + er) * ldc + n0 + wc * 64 + ec;
            *(short8*)((short*)Cv + cb)     = v0;
            *(short8*)((short*)Cv + cb + 8) = v1;
            __builtin_amdgcn_sched_barrier(0);
        }
    } else {
#pragma unroll
        for (int mi = 0; mi < 4; ++mi)
#pragma unroll
            for (int ni = 0; ni < 4; ++ni) {
                int gc = n0 + wc * 64 + ni * 16 + l16;
#pragma unroll
                for (int r = 0; r < 4; ++r) {
                    float x = acc[mi][ni][r] + bv[ni];
                    if (ACT == 1) x = eluf(x);
                    ((float*)Cv)[(long)(cm0 + wr * 64 + mi * 16 + quad * 4 + r) * ldc + gc] = x;
                }
            }
    }
}

// ---------------------------------------------------------------------------
// 4-wave 128x128 GEMM core, BK=128: the three big M=16384 GEMMs.
// Ls = 32768 shorts (64KB): A = 4 chunks x [128][32], B same at +16384.
// 4 barrier pairs per K=512 pass, 64 MFMA per wave per drain.
// OUTB: 1 = bf16 C, 2 = hs-mode (dot with hq -> hsp partials).
// ---------------------------------------------------------------------------
template <int ACT, int OUTB, int DUAL>
__device__ __forceinline__ void gcoreB(
    const short* __restrict__ A, const short* __restrict__ B,
    const short* __restrict__ A2, const short* __restrict__ B2,
    const float* __restrict__ bias, void* __restrict__ Cv,
    int ldc, int K, int m0, int n0, int cm0, short* Ls,
    const float* __restrict__ hq, float* __restrict__ hsp)
{
    short* Al = Ls;
    short* Bl = Ls + 16384;
    const int tid  = threadIdx.x;
    const int lane = tid & 63;
    const int w    = tid >> 6;
    const int wr   = w >> 1, wc = w & 1;
    const int l16  = lane & 15, quad = lane >> 4;

    const int srow = w * 16 + (lane >> 2);
    const int scol = (lane & 3) * 8;

    f32x4 acc[4][4];
#pragma unroll
    for (int i = 0; i < 4; ++i)
#pragma unroll
        for (int j = 0; j < 4; ++j) { acc[i][j][0]=0.f; acc[i][j][1]=0.f; acc[i][j][2]=0.f; acc[i][j][3]=0.f; }

    short* lA = Al + w * 512;
    short* lB = Bl + w * 512;
    const long rstep = (long)64 * K;

    for (int rep = 0; rep <= DUAL; ++rep) {
        const short* Ag = (rep ? A2 : A) + (long)(m0 + srow) * K + scol;
        const short* Bg = (rep ? B2 : B) + (long)(n0 + srow) * K + scol;
        for (int kt = 0; kt < K; kt += 128) {
            __syncthreads();
#pragma unroll
            for (int h = 0; h < 4; ++h) {
                gld16(Ag + kt + h * 32,         lA + h * 4096);
                gld16(Ag + kt + h * 32 + rstep, lA + h * 4096 + 2048);
                gld16(Bg + kt + h * 32,         lB + h * 4096);
                gld16(Bg + kt + h * 32 + rstep, lB + h * 4096 + 2048);
            }
            __syncthreads();
#pragma unroll
            for (int h = 0; h < 4; ++h) {
                short8 af[4], bf4[4];
#pragma unroll
                for (int mi = 0; mi < 4; ++mi)
                    af[mi] = *(const short8*)(Al + h * 4096 + (wr * 64 + mi * 16 + l16) * 32 + quad * 8);
#pragma unroll
                for (int ni = 0; ni < 4; ++ni)
                    bf4[ni] = *(const short8*)(Bl + h * 4096 + (wc * 64 + ni * 16 + l16) * 32 + quad * 8);
#pragma unroll
                for (int mi = 0; mi < 4; ++mi)
#pragma unroll
                    for (int ni = 0; ni < 4; ++ni)
                        acc[mi][ni] = __builtin_amdgcn_mfma_f32_16x16x32_bf16(af[mi], bf4[ni], acc[mi][ni], 0, 0, 0);
            }
        }
    }

    __syncthreads();

    float bv[4];
#pragma unroll
    for (int ni = 0; ni < 4; ++ni)
        bv[ni] = bias ? bias[n0 + wc * 64 + ni * 16 + l16] : 0.f;

    if (OUTB == 1) {
        short* eb = Ls + w * 1152;
        const int er = lane >> 2;
        const int ec = (lane & 3) * 16;
#pragma unroll
        for (int mi = 0; mi < 4; ++mi) {
#pragma unroll
            for (int ni = 0; ni < 4; ++ni)
#pragma unroll
                for (int r = 0; r < 4; ++r) {
                    float x = acc[mi][ni][r] + bv[ni];
                    if (ACT == 1) x = eluf(x);
                    else if (ACT == 2) x = tanhf(x);
                    eb[(quad * 4 + r) * 72 + ni * 16 + l16] = f2bs(x);
                }
            __builtin_amdgcn_sched_barrier(0);
            short8 v0 = *(const short8*)&eb[er * 72 + ec];
            short8 v1 = *(const short8*)&eb[er * 72 + ec + 8];
            long cb = (long)(cm0 + wr * 64 + mi * 16 + er) * ldc + n0 + wc * 64 + ec;
            *(short8*)((short*)Cv + cb)     = v0;
            *(short8*)((short*)Cv + cb + 8) = v1;
            __builtin_amdgcn_sched_barrier(0);
        }
    } else if (OUTB == 2) {
        const int n_w = (cm0 + wr * 64) >> 6;
        float hqv[4];
#pragma unroll
        for (int ni = 0; ni < 4; ++ni)
            hqv[ni] = hq[(long)n_w * 512 + n0 + wc * 64 + ni * 16 + l16];
        float* red = (float*)Ls;                   // [4 waves][64 rows]
#pragma unroll
        for (int mi = 0; mi < 4; ++mi)
#pragma unroll
            for (int r = 0; r < 4; ++r) {
                float p = 0.f;
#pragma unroll
                for (int ni = 0; ni < 4; ++ni) {
                    float x = acc[mi][ni][r] + bv[ni];
                    if (ACT == 1) x = eluf(x);
                    p += x * hqv[ni];
                }
                p += __shfl_xor(p, 1);
                p += __shfl_xor(p, 2);
                p += __shfl_xor(p, 4);
                p += __shfl_xor(p, 8);
                if (l16 == 0) red[w * 64 + mi * 16 + quad * 4 + r] = p;
            }
        __syncthreads();
        if (tid < 128) {
            int wr2 = tid >> 6, rw = tid & 63;
            float v = red[(wr2 * 2 + 0) * 64 + rw] + red[(wr2 * 2 + 1) * 64 + rw];
            hsp[(long)(n0 >> 7) * 16384 + cm0 + tid] = v;
        }
    }
}

// XCD-swizzled big GEMM (BK=128 core). Grid = 4*NG 1D blocks; the 4 x-siblings
// of one A-tile share id mod 8 -> same XCD under round-robin dispatch.
template <int ACT, int OUTB, int DUAL, int NYL2>
__global__ __launch_bounds__(256) void mgemm_sw(
    const short* __restrict__ A, long sAz,
    const short* __restrict__ B, long sBz,
    const short* __restrict__ A2, long sA2z,
    const short* __restrict__ B2,
    const float* __restrict__ bias,
    void* __restrict__ Cv, long sCz, int ldc, int K)
{
    __shared__ short Ls[32768];
    const int bid = blockIdx.x;
    const int g = (bid & 7) + 8 * (bid >> 5);
    const int x = (bid >> 3) & 3;
    const int y = g & ((1 << NYL2) - 1);
    const int z = g >> NYL2;
    void* C = (void*)((short*)Cv + (long)z * sCz);
    const short* A2z = DUAL ? (A2 + (long)z * sA2z) : nullptr;
    gcoreB<ACT, OUTB, DUAL>(A + (long)z * sAz, B + (long)z * sBz, A2z, B2, bias, C,
                            ldc, K, y * 128, x * 128, y * 128, Ls, nullptr, nullptr);
}

// hs GEMM, swizzled: g = y in [0,128)
__global__ __launch_bounds__(256) void mgemm_hs(
    const short* __restrict__ A, const short* __restrict__ B,
    const float* __restrict__ bias, const float* __restrict__ hq, float* __restrict__ hsp)
{
    __shared__ short Ls[32768];
    const int bid = blockIdx.x;
    const int y = (bid & 7) + 8 * (bid >> 5);
    const int x = (bid >> 3) & 3;
    gcoreB<1, 2, 0>(A, B, nullptr, nullptr, bias, nullptr, 512, 512,
                    y * 128, x * 128, y * 128, Ls, hq, hsp);
}

// qall (48) | qe (16) | tk (128) in one launch (BK=64 core)
__global__ __launch_bounds__(256) void mgemm_multi(
    const short* __restrict__ decb, const short* __restrict__ WTall, float* __restrict__ qall,
    const short* __restrict__ embAll, const short* __restrict__ WTe, float* __restrict__ qe,
    const short* __restrict__ WTk, const float* __restrict__ b_tk, short* __restrict__ tkb)
{
    __shared__ short Ls[16384];
    int id = blockIdx.x;
    if (id < 48) {
        int y = id >> 4, x = id & 15;
        gcore<0, 0>(decb, WTall, nullptr, qall, 2048, 512, y * 128, x * 128, y * 128, Ls);
    } else if (id < 64) {
        int id2 = id - 48, y = id2 >> 2, x = id2 & 3;
        gcore<0, 0>(embAll, WTe, nullptr, qe, 512, 512, y * 128, x * 128, y * 128, Ls);
    } else {
        int id3 = id - 64, y = id3 >> 2, x = id3 & 3;
        gcore<1, 1>(embAll, WTk, b_tk, tkb, 512, 512, 512 + y * 128, x * 128, y * 128, Ls);
    }
}

// ---------------------------------------------------------------------------
// prep (vectorized): float4 casts | 2-rows/block float4 gathers | transposes
// ---------------------------------------------------------------------------
struct WTDesc { const float* src[9]; short* dst[9]; };

__global__ __launch_bounds__(256) void prep(
    const float* __restrict__ dec_out, const float* __restrict__ history,
    short* __restrict__ decb,
    const float* __restrict__ emb, const int* __restrict__ head, const int* __restrict__ tail,
    short* __restrict__ embAll, WTDesc wd)
{
    __shared__ float t[32][33];
    const int id = blockIdx.x, tid = threadIdx.x;
    if (id < 132) {
        int i = (id * 256 + tid) * 4;
        float4 v = (i < 131072) ? *(const float4*)(dec_out + i)
                                : *(const float4*)(history + (i - 131072));
        short4 o;
        o.x = f2bs(v.x); o.y = f2bs(v.y); o.z = f2bs(v.z); o.w = f2bs(v.w);
        *(short4*)(decb + i) = o;
    } else if (id < 132 + 2304) {
        int r = (id - 132) * 2 + (tid >> 7);
        int c4 = (tid & 127) * 4;
        int idx = (r < 512) ? head[r] : tail[r - 512];
        float4 v = *(const float4*)(emb + (long)idx * 512 + c4);
        short4 o;
        o.x = f2bs(v.x); o.y = f2bs(v.y); o.z = f2bs(v.z); o.w = f2bs(v.w);
        *(short4*)(embAll + (long)r * 512 + c4) = o;
    } else {
        int q = id - 2436;
        int z = q >> 8, xy = q & 255;
        int x = xy & 15, y = xy >> 4;
        const float* src = wd.src[z];
        short* dst = wd.dst[z];
        int k0 = y * 32, n0 = x * 32;
        int tx = tid & 31, ty = tid >> 5;
#pragma unroll
        for (int i = 0; i < 32; i += 8)
            t[ty + i][tx] = src[(long)(k0 + ty + i) * 512 + n0 + tx];
        __syncthreads();
#pragma unroll
        for (int i = 0; i < 32; i += 8)
            dst[(long)(n0 + ty + i) * 512 + k0 + tx] = f2bs(t[tx][ty + i]);
    }
}

// ---------------------------------------------------------------------------
// L3: build_tq (8192) | tkWT GEMM (128) | hq build (128)
// ---------------------------------------------------------------------------
__global__ __launch_bounds__(256) void l3_kernel(
    const float* __restrict__ qall, const float* __restrict__ qe,
    const float* __restrict__ b_tq, short* __restrict__ tqb,
    const short* __restrict__ WTo1, const short* __restrict__ tkb, short* __restrict__ tkWTb,
    const float* __restrict__ b_hq, float* __restrict__ hqf)
{
    __shared__ short Ls[16384];
    if (blockIdx.x < 8192) {
        long gid = (long)blockIdx.x * 256 + threadIdx.x;
        int r = (int)(gid >> 7), j0 = ((int)gid & 127) * 4;
        int b = r >> 11, rem = r & 2047, s = rem >> 6, h = rem & 63;
        float4 d = *(const float4*)(qall + (long)(b * 32 + s) * 2048 + j0);
        float4 q = *(const float4*)(qall + (long)(256 + b) * 2048 + 1024 + j0);
        float4 e = *(const float4*)(qe + (long)(b * 64 + h) * 512 + j0);
        float4 bb = *(const float4*)(b_tq + j0);
        short4 o;
        o.x = f2bs(eluf(d.x + q.x + e.x + bb.x));
        o.y = f2bs(eluf(d.y + q.y + e.y + bb.y));
        o.z = f2bs(eluf(d.z + q.z + e.z + bb.z));
        o.w = f2bs(eluf(d.w + q.w + e.w + bb.w));
        *(short4*)(tqb + (long)r * 512 + j0) = o;
    } else if (blockIdx.x < 8320) {
        int id2 = blockIdx.x - 8192;
        int z = id2 >> 4, r = id2 & 15;
        int x = r & 3, y = r >> 2;
        gcore<0, 1>(WTo1, tkb + (long)z * 262144, nullptr,
                    tkWTb + (long)z * 262144, 512, 512, y * 128, x * 128, y * 128, Ls);
    } else {
        long gid = (long)(blockIdx.x - 8320) * 256 + threadIdx.x;
        int n = (int)(gid >> 7), j0 = ((int)gid & 127) * 4;
        int b = n >> 5;
        float4 d = *(const float4*)(qall + (long)n * 2048 + 512 + j0);
        float4 h2 = *(const float4*)(qall + (long)(256 + b) * 2048 + 1536 + j0);
        float4 bb = *(const float4*)(b_hq + j0);
        float4 o;
        o.x = eluf(d.x + h2.x + bb.x);
        o.y = eluf(d.y + h2.y + bb.y);
        o.z = eluf(d.z + h2.z + bb.z);
        o.w = eluf(d.w + h2.w + bb.w);
        *(float4*)(hqf + (long)n * 512 + j0) = o;
    }
}

// mask + row softmax over 512: bf16 scores -> bf16 P. 4 rows/block, short8 loads.
__global__ __launch_bounds__(256) void sm_kernel(
    const short* __restrict__ sc, const int* __restrict__ adj, const int* __restrict__ dup,
    short* __restrict__ Pb)
{
    int w = threadIdx.x >> 6, lane = threadIdx.x & 63;
    long r = (long)blockIdx.x * 4 + w;
    int b = (int)(r >> 11), rem = (int)(r & 2047), s = rem >> 6, h = rem & 63;
    const short* row = sc + r * 512 + lane * 8;
    const int* adjr = adj + ((long)(b * 64 + h)) * 512 + lane * 8;
    const int* dupr = dup + ((long)(b * 32 + s)) * 512 + lane * 8;
    short8 v8 = *(const short8*)row;
    int4 a0 = *(const int4*)adjr, a1 = *(const int4*)(adjr + 4);
    int4 d0 = *(const int4*)dupr, d1 = *(const int4*)(dupr + 4);
    int am[8] = {a0.x, a0.y, a0.z, a0.w, a1.x, a1.y, a1.z, a1.w};
    int dm[8] = {d0.x, d0.y, d0.z, d0.w, d1.x, d1.y, d1.z, d1.w};
    float v[8];
    float m = -INFINITY;
#pragma unroll
    for (int i = 0; i < 8; ++i) {
        v[i] = (am[i] && !dm[i]) ? b2f(v8[i]) : -INFINITY;
        m = fmaxf(m, v[i]);
    }
#pragma unroll
    for (int d = 32; d >= 1; d >>= 1) m = fmaxf(m, __shfl_xor(m, d));
    float sum = 0.f;
#pragma unroll
    for (int i = 0; i < 8; ++i) {
        float e = (m == -INFINITY) ? 0.f : expf(v[i] - m);
        v[i] = e; sum += e;
    }
#pragma unroll
    for (int d = 32; d >= 1; d >>= 1) sum += __shfl_xor(sum, d);
    float inv = sum > 0.f ? 1.f / sum : 0.f;
    short8 o;
#pragma unroll
    for (int i = 0; i < 8; ++i) o[i] = f2bs(v[i] * inv);
    *(short8*)(Pb + r * 512 + lane * 8) = o;
}

// head softmax (from hsp partials) + prob + log; one block per n
__global__ __launch_bounds__(256) void fused_head(
    const float* __restrict__ hsp, const int* __restrict__ head,
    const short* __restrict__ ta, float* __restrict__ out)
{
    int n = blockIdx.x, b = n >> 5;
    int tid = threadIdx.x;
    __shared__ float hal[64];
    __shared__ float part[4][512];

    if (tid < 64) {
        float sv_raw = hsp[n * 64 + tid] + hsp[16384 + n * 64 + tid]
                     + hsp[2 * 16384 + n * 64 + tid] + hsp[3 * 16384 + n * 64 + tid];
        int hv = head[b * 64 + tid];
        unsigned long long ball = __ballot(hv != 0);
        int len = __popcll(ball);
        float sv = (tid < len) ? sv_raw : -INFINITY;
        float m = sv;
#pragma unroll
        for (int d = 32; d >= 1; d >>= 1) m = fmaxf(m, __shfl_xor(m, d));
        float e = expf(sv - m);
        float sum = e;
#pragma unroll
        for (int d = 32; d >= 1; d >>= 1) sum += __shfl_xor(sum, d);
        hal[tid] = e / sum;
    }
    __syncthreads();

    {
        int w = tid >> 6, lane = tid & 63;
        const short* tab = ta + (long)n * 64 * 512 + (long)(w * 16) * 512 + lane * 8;
        float acc[8] = {};
#pragma unroll
        for (int k = 0; k < 16; ++k) {
            float a = hal[w * 16 + k];
            short8 tv = *(const short8*)(tab + (long)k * 512);
#pragma unroll
            for (int u = 0; u < 8; ++u) acc[u] += a * b2f(tv[u]);
        }
        float4* pp = (float4*)&part[w][lane * 8];
        pp[0] = make_float4(acc[0], acc[1], acc[2], acc[3]);
        pp[1] = make_float4(acc[4], acc[5], acc[6], acc[7]);
    }
    __syncthreads();

    for (int t = tid; t < 512; t += 256) {
        float a = part[0][t] + part[1][t] + part[2][t] + part[3][t];
        out[(long)n * 512 + t] = logf(a + 1e-20f);
    }
}

extern "C" void kernel_launch(void* const* d_in, const int* in_sizes, int n_in,
                              void* d_out, int out_size, void* d_ws, size_t ws_size,
                              hipStream_t stream)
{
    const float* dec_out = (const float*)d_in[0];
    const float* history = (const float*)d_in[1];
    const int*   head    = (const int*)d_in[2];
    const int*   tail    = (const int*)d_in[3];
    const int*   adj     = (const int*)d_in[4];
    const int*   dup     = (const int*)d_in[5];
    const float* emb     = (const float*)d_in[6];
    const float* W_tq    = (const float*)d_in[7];
    const float* b_tq    = (const float*)d_in[8];
    const float* W_tk    = (const float*)d_in[9];
    const float* b_tk    = (const float*)d_in[10];
    const float* W_tout  = (const float*)d_in[11];
    const float* W_hq    = (const float*)d_in[12];
    const float* b_hq    = (const float*)d_in[13];
    const float* W_hk    = (const float*)d_in[14];
    const float* b_hk    = (const float*)d_in[15];
    float* out = (float*)d_out;

    char* ws = (char*)d_ws;
    auto alloc = [&](size_t bytes) -> void* {
        char* p = ws;
        ws += (bytes + 255) & ~(size_t)255;
        return (void*)p;
    };
    short* decb   = (short*)alloc((size_t)384 * 512 * 2);    // dec 0..255, hist 256..263
    short* embAll = (short*)alloc((size_t)4608 * 512 * 2);   // head 0..511, tail 512..4607
    short* WT     = (short*)alloc((size_t)9 * 512 * 512 * 2);
    float* qall   = (float*)alloc((size_t)384 * 2048 * 4);   // [qd|hqp|qh'|hq2']
    float* qe     = (float*)alloc((size_t)512 * 512 * 4);
    float* hqf    = (float*)alloc((size_t)256 * 512 * 4);
    float* hsp    = (float*)alloc((size_t)4 * 16384 * 4);    // hscores col-block partials
    short* tkb    = (short*)alloc((size_t)4096 * 512 * 2);
    short* tkWTb  = (short*)alloc((size_t)4096 * 512 * 2);
    short* tqb    = (short*)alloc((size_t)16384 * 512 * 2);
    short* scb    = (short*)alloc((size_t)16384 * 512 * 2);  // scores -> gh
    short* Pb     = (short*)alloc((size_t)16384 * 512 * 2);  // tail_attn (to the end)
    short* ghb = scb;   // scores dead after sm

    // WT slab: 0 Wd^T | 1 Whq1^T | 2 Wtq2^T | 3 Whq2^T | 4 We^T | 5 Wtk^T
    //          6 Wtout1^T | 7 Wtout2^T | 8 Whk^T
    WTDesc wd;
    wd.src[0] = W_tq;               wd.dst[0] = WT;
    wd.src[1] = W_hq;               wd.dst[1] = WT + (size_t)1 * 262144;
    wd.src[2] = W_tq + 512 * 512;   wd.dst[2] = WT + (size_t)2 * 262144;
    wd.src[3] = W_hq + 512 * 512;   wd.dst[3] = WT + (size_t)3 * 262144;
    wd.src[4] = W_tq + 1024 * 512;  wd.dst[4] = WT + (size_t)4 * 262144;
    wd.src[5] = W_tk;               wd.dst[5] = WT + (size_t)5 * 262144;
    wd.src[6] = W_tout;             wd.dst[6] = WT + (size_t)6 * 262144;
    wd.src[7] = W_tout + 512 * 512; wd.dst[7] = WT + (size_t)7 * 262144;
    wd.src[8] = W_hk;               wd.dst[8] = WT + (size_t)8 * 262144;

    // 1: casts / gathers / weight transposes
    prep<<<4740, 256, 0, stream>>>(dec_out, history, decb, emb, head, tail, embAll, wd);
    // 2: qall | qe | tk
    mgemm_multi<<<192, 256, 0, stream>>>(decb, WT, qall, embAll, WT + (size_t)4 * 262144, qe,
                                         WT + (size_t)5 * 262144, b_tk, tkb);
    // 3: build tq | tkWT = Wtout1^T @ tk^T (per b) | build hq
    l3_kernel<<<8448, 256, 0, stream>>>(qall, qe, b_tq, tqb, WT + (size_t)6 * 262144, tkb, tkWTb,
                                        b_hq, hqf);
    // 4: raw scores = tq @ tk^T (per b), BK=128, XCD-swizzled (y16 x z8)
    mgemm_sw<0, 1, 0, 4><<<512, 256, 0, stream>>>(
        tqb, (long)2048 * 512, tkb, 262144, nullptr, 0, nullptr, nullptr,
        scb, (long)2048 * 512, 512, 512);
    // 5: mask + softmax -> P
    sm_kernel<<<4096, 256, 0, stream>>>(scb, adj, dup, Pb);
    // 6: gh = tanh(P @ tkWT^T + tq @ Wtout2^T), BK=128, swizzled (over scb)
    mgemm_sw<2, 1, 1, 4><<<512, 256, 0, stream>>>(
        Pb, (long)2048 * 512, tkWTb, 262144, tqb, (long)2048 * 512, WT + (size_t)7 * 262144,
        nullptr, ghb, (long)2048 * 512, 512, 512);
    // 7: hscores partials = elu(gh @ Whk^T + b_hk) . hq, BK=128, swizzled
    mgemm_hs<<<512, 256, 0, stream>>>(ghb, WT + (size_t)8 * 262144, b_hk, hqf, hsp);
    // 8: head softmax + prob + log
    fused_head<<<256, 256, 0, stream>>>(hsp, head, Pb, out);
}